// Round 1
// baseline (1685.280 us; speedup 1.0000x reference)
//
#include <hip/hip_runtime.h>
#include <hip/hip_bf16.h>

// ---------------- problem constants ----------------
#define N_IN    32768
#define K_EMB   4096
#define D_EMB   256
#define ND      (N_IN * (size_t)D_EMB)          // 8388608
#define NK      ((size_t)N_IN * K_EMB)          // 134217728
// d_out layout (floats): [0]=loss, [1..1+ND)=quantized_st, [1+ND]=perplexity, [2+ND..)=encodings
#define OUT_PERP_OFF  (1 + ND)                  // 8388609
#define OUT_ENC_OFF   (2 + ND)                  // 8388610

// ---------------- ws layout (bytes) ----------------
#define WS_SUMW2   0          // 4096 f
#define WS_COUNTS  16384      // 4096 i
#define WS_LOSS    32768      // 1 f
#define WS_IDX     36864      // 32768 i
#define WS_PVAL    167936     // 65536 f  (2 splits)
#define WS_PIDX    430080     // 65536 i

// ---------------- k1: sum of squares per codeword ----------------
__global__ void vq_sumw2(const float* __restrict__ w, float* __restrict__ sumw2) {
    int lane = threadIdx.x & 63;
    int row  = blockIdx.x * 4 + (threadIdx.x >> 6);
    const float4* gw = (const float4*)w;
    float4 v = gw[(size_t)row * 64 + lane];
    float s = v.x * v.x + v.y * v.y + v.z * v.z + v.w * v.w;
    #pragma unroll
    for (int off = 32; off; off >>= 1) s += __shfl_down(s, off, 64);
    if (lane == 0) sumw2[row] = s;
}

// ---------------- k2: fused distance GEMM + argmin ----------------
// block: 256 threads, tile 128 rows x 128 codewords, split-K over codeword halves.
// score(n,c) = sumw2[c] - 2 * dot(x_n, w_c)   (|x|^2 dropped: row-constant)
__global__ __launch_bounds__(256) void vq_argmin(
        const float* __restrict__ x, const float* __restrict__ w,
        const float* __restrict__ sumw2,
        float* __restrict__ pval, int* __restrict__ pidx) {
    __shared__ float4 sx[128 * 16];   // 32 KB, element (r,dq) at r*16 + (dq ^ (r>>3))
    __shared__ float4 sw[128 * 16];   // 32 KB
    const int t  = threadIdx.x;
    const int tx = t & 15, ty = t >> 4;
    const int rowBase = blockIdx.x * 128;
    const int split   = blockIdx.y;            // 0 or 1
    const float4* gx = (const float4*)x;
    const float4* gw = (const float4*)w;

    float best[8];
    int   bidx[8];
    #pragma unroll
    for (int i = 0; i < 8; ++i) { best[i] = 3.0e38f; bidx[i] = 0; }

    for (int ct = 0; ct < 16; ++ct) {
        const int colBase = (split * 16 + ct) * 128;
        float acc[8][8] = {};
        for (int dc = 0; dc < 4; ++dc) {
            __syncthreads();   // protect LDS from previous iteration's readers
            #pragma unroll
            for (int i = 0; i < 8; ++i) {
                int idx = i * 256 + t;
                int r = idx >> 4, dq = idx & 15;
                int ph = r * 16 + (dq ^ (r >> 3));
                sx[ph] = gx[(size_t)(rowBase + r) * 64 + dc * 16 + dq];
                sw[ph] = gw[(size_t)(colBase + r) * 64 + dc * 16 + dq];
            }
            __syncthreads();
            #pragma unroll 2
            for (int dq = 0; dq < 16; ++dq) {
                float4 xv[8], wv[8];
                const int dqx = dq ^ ty;   // rows r=ty*8+i -> r>>3 == ty
                const int dqw = dq ^ tx;   // cols c=tx*8+j -> c>>3 == tx
                #pragma unroll
                for (int i = 0; i < 8; ++i) xv[i] = sx[(ty * 8 + i) * 16 + dqx];
                #pragma unroll
                for (int j = 0; j < 8; ++j) wv[j] = sw[(tx * 8 + j) * 16 + dqw];
                #pragma unroll
                for (int i = 0; i < 8; ++i)
                    #pragma unroll
                    for (int j = 0; j < 8; ++j)
                        acc[i][j] += xv[i].x * wv[j].x + xv[i].y * wv[j].y
                                   + xv[i].z * wv[j].z + xv[i].w * wv[j].w;
            }
        }
        // epilogue: scores + running argmin (ascending c, strict < keeps lowest idx)
        #pragma unroll
        for (int j = 0; j < 8; ++j) {
            int c = colBase + tx * 8 + j;
            float s2 = sumw2[c];
            #pragma unroll
            for (int i = 0; i < 8; ++i) {
                float s = s2 - 2.0f * acc[i][j];
                if (s < best[i]) { best[i] = s; bidx[i] = c; }
            }
        }
    }
    // reduce across the 16 tx lanes sharing each row (contiguous 16-lane groups)
    #pragma unroll
    for (int i = 0; i < 8; ++i) {
        float v = best[i]; int bi = bidx[i];
        #pragma unroll
        for (int m = 1; m <= 8; m <<= 1) {
            float ov = __shfl_xor(v, m, 64);
            int   oi = __shfl_xor(bi, m, 64);
            if (ov < v || (ov == v && oi < bi)) { v = ov; bi = oi; }
        }
        if (tx == 0) {
            int row = rowBase + ty * 8 + i;
            pval[split * N_IN + row] = v;
            pidx[split * N_IN + row] = bi;
        }
    }
}

// ---------------- k3: merge the two K-splits, histogram ----------------
__global__ void vq_merge(const float* __restrict__ pval, const int* __restrict__ pidx,
                         int* __restrict__ indices, int* __restrict__ counts) {
    int n = blockIdx.x * 256 + threadIdx.x;
    float v0 = pval[n], v1 = pval[N_IN + n];
    int   i0 = pidx[n], i1 = pidx[N_IN + n];
    int bi = (v1 < v0) ? i1 : i0;   // tie -> split 0 (lower index)
    indices[n] = bi;
    atomicAdd(&counts[bi], 1);
}

// ---------------- k4: gather quantized, straight-through, loss partial ----------------
__global__ void vq_quant(const float* __restrict__ x, const float* __restrict__ w,
                         const int* __restrict__ indices, float* __restrict__ out,
                         float* __restrict__ lossacc) {
    const float4* gx = (const float4*)x;
    const float4* gw = (const float4*)w;
    float* q = out + 1;   // quantized_st base (4B-aligned only -> scalar stores)
    size_t tid = (size_t)blockIdx.x * 256 + threadIdx.x;
    size_t stride = (size_t)gridDim.x * 256;
    float s = 0.0f;
    for (size_t f = tid; f < (ND / 4); f += stride) {
        int n = (int)(f >> 6), d4 = (int)(f & 63);
        float4 xv = gx[f];
        float4 ev = gw[(size_t)indices[n] * 64 + d4];
        float dx = ev.x - xv.x, dy = ev.y - xv.y, dz = ev.z - xv.z, dw = ev.w - xv.w;
        s += dx * dx + dy * dy + dz * dz + dw * dw;
        size_t o = (size_t)n * 256 + (size_t)d4 * 4;
        q[o]     = xv.x + dx;
        q[o + 1] = xv.y + dy;
        q[o + 2] = xv.z + dz;
        q[o + 3] = xv.w + dw;
    }
    #pragma unroll
    for (int off = 32; off; off >>= 1) s += __shfl_down(s, off, 64);
    if ((threadIdx.x & 63) == 0) atomicAdd(lossacc, s);
}

// ---------------- k5: scatter ones into encodings ----------------
__global__ void vq_scatter(const int* __restrict__ indices, float* __restrict__ enc) {
    int n = blockIdx.x * 256 + threadIdx.x;
    enc[(size_t)n * K_EMB + indices[n]] = 1.0f;
}

// ---------------- k6: finalize loss + perplexity ----------------
__global__ void vq_final(const int* __restrict__ counts, const float* __restrict__ lossacc,
                         float* __restrict__ out) {
    __shared__ float red[4];
    int t = threadIdx.x;
    float e = 0.0f;
    #pragma unroll
    for (int k = 0; k < 16; ++k) {
        float p = (float)counts[t + 256 * k] * (1.0f / 32768.0f);
        e += p * logf(p + 1e-10f);
    }
    #pragma unroll
    for (int off = 32; off; off >>= 1) e += __shfl_down(e, off, 64);
    if ((t & 63) == 0) red[t >> 6] = e;
    __syncthreads();
    if (t == 0) {
        float ent = red[0] + red[1] + red[2] + red[3];
        out[0] = 1.25f * lossacc[0] / 8388608.0f;   // q_latent + 0.25*e_latent (identical means)
        out[OUT_PERP_OFF] = expf(-ent);
    }
}

extern "C" void kernel_launch(void* const* d_in, const int* in_sizes, int n_in,
                              void* d_out, int out_size, void* d_ws, size_t ws_size,
                              hipStream_t stream) {
    const float* x = (const float*)d_in[0];
    const float* w = (const float*)d_in[1];
    float* out = (float*)d_out;
    char* ws = (char*)d_ws;
    float* sumw2   = (float*)(ws + WS_SUMW2);
    int*   counts  = (int*)  (ws + WS_COUNTS);
    float* lossacc = (float*)(ws + WS_LOSS);
    int*   indices = (int*)  (ws + WS_IDX);
    float* pval    = (float*)(ws + WS_PVAL);
    int*   pidx    = (int*)  (ws + WS_PIDX);

    // zero counts + loss accumulator (ws is poisoned 0xAA before every launch)
    hipMemsetAsync(ws + WS_COUNTS, 0, 16384 + 4, stream);
    // zero the 512 MB encodings block of d_out
    hipMemsetAsync(out + OUT_ENC_OFF, 0, NK * sizeof(float), stream);

    vq_sumw2<<<K_EMB / 4, 256, 0, stream>>>(w, sumw2);
    dim3 g2(N_IN / 128, 2);
    vq_argmin<<<g2, 256, 0, stream>>>(x, w, sumw2, pval, pidx);
    vq_merge<<<N_IN / 256, 256, 0, stream>>>(pval, pidx, indices, counts);
    vq_quant<<<2048, 256, 0, stream>>>(x, w, indices, out, lossacc);
    vq_scatter<<<N_IN / 256, 256, 0, stream>>>(indices, out + OUT_ENC_OFF);
    vq_final<<<1, 256, 0, stream>>>(counts, lossacc, out);
}

// Round 2
// 1052.476 us; speedup vs baseline: 1.6013x; 1.6013x over previous
//
#include <hip/hip_runtime.h>
#include <hip/hip_bf16.h>

// ---------------- problem constants ----------------
#define N_IN    32768
#define K_EMB   4096
#define D_EMB   256
#define ND      (N_IN * (size_t)D_EMB)          // 8388608
#define NK      ((size_t)N_IN * K_EMB)          // 134217728
// d_out layout (floats): [0]=loss, [1..1+ND)=quantized_st, [1+ND]=perplexity, [2+ND..)=encodings
#define OUT_PERP_OFF  (1 + ND)                  // 8388609
#define OUT_ENC_OFF   (2 + ND)                  // 8388610

// ---------------- small ws layout (bytes) ----------------
#define WS_SUMW2   0          // 4096 f
#define WS_COUNTS  16384      // 4096 i
#define WS_LOSS    32768      // 1 f
#define WS_IDX     36864      // 32768 i

// scratch inside encodings region (bytes from scratch base, 16B aligned):
//   A' = [x_hi | x_lo]  N x 512 bf16   = 33554432 B
//   B' = [w_hi | w_lo]  K x 512 bf16   =  4194304 B
//   PV 32x32768 f32 = 4 MB ; PI same
#define SCR_A   0
#define SCR_B   33554432
#define SCR_PV  37748736
#define SCR_PI  41943040

typedef short bf16x8 __attribute__((ext_vector_type(8)));
typedef float f32x4  __attribute__((ext_vector_type(4)));

__device__ __forceinline__ void gload_lds16(const void* g, void* l) {
    __builtin_amdgcn_global_load_lds(
        (const __attribute__((address_space(1))) unsigned int*)g,
        (__attribute__((address_space(3))) unsigned int*)l, 16, 0, 0);
}

__device__ __forceinline__ ushort bf_bits(__hip_bfloat16 h) {
    union { __hip_bfloat16 h; ushort u; } cv; cv.h = h; return cv.u;
}
__device__ __forceinline__ void split2(float v, ushort& hi, ushort& lo) {
    __hip_bfloat16 h = __float2bfloat16(v);
    float hf = __bfloat162float(h);
    hi = bf_bits(h);
    lo = bf_bits(__float2bfloat16(v - hf));
}

// ---------------- k0: fp32 -> (hi, lo) bf16 split for x and w ----------------
__global__ void vq_convert(const float* __restrict__ x, const float* __restrict__ w,
                           ushort* __restrict__ A, ushort* __restrict__ B) {
    const size_t XQ = ND / 4;            // 2097152 float4's of x
    const size_t WQ = (size_t)K_EMB * D_EMB / 4;  // 262144
    size_t f = (size_t)blockIdx.x * 256 + threadIdx.x;
    size_t stride = (size_t)gridDim.x * 256;
    for (; f < XQ + WQ; f += stride) {
        float4 v; ushort* dh; ushort* dl;
        if (f < XQ) {
            int n = (int)(f >> 6), d4 = (int)(f & 63);
            v = ((const float4*)x)[f];
            dh = A + (size_t)n * 512 + d4 * 4;
            dl = dh + 256;
        } else {
            size_t f2 = f - XQ;
            int c = (int)(f2 >> 6), d4 = (int)(f2 & 63);
            v = ((const float4*)w)[f2];
            dh = B + (size_t)c * 512 + d4 * 4;
            dl = dh + 256;
        }
        ushort4 hv, lv;
        split2(v.x, hv.x, lv.x); split2(v.y, hv.y, lv.y);
        split2(v.z, hv.z, lv.z); split2(v.w, hv.w, lv.w);
        *(ushort4*)dh = hv;
        *(ushort4*)dl = lv;
    }
}

// ---------------- k1: sum of squares per codeword (exact fp32) ----------------
__global__ void vq_sumw2(const float* __restrict__ w, float* __restrict__ sumw2) {
    int lane = threadIdx.x & 63;
    int row  = blockIdx.x * 4 + (threadIdx.x >> 6);
    const float4* gw = (const float4*)w;
    float4 v = gw[(size_t)row * 64 + lane];
    float s = v.x * v.x + v.y * v.y + v.z * v.z + v.w * v.w;
    #pragma unroll
    for (int off = 32; off; off >>= 1) s += __shfl_down(s, off, 64);
    if (lane == 0) sumw2[row] = s;
}

// ---------------- k2: bf16-split MFMA GEMM + fused argmin ----------------
// 128x128 tile, 4 waves (2x2), BK=64, Kred=768 (3 terms), m97-style staging.
// score(n,c) = sumw2[c] - 2*dot(x_n, w_c)
__global__ __launch_bounds__(256) void vq_gemm_argmin(
        const ushort* __restrict__ A, const ushort* __restrict__ B,
        const float* __restrict__ sumw2,
        float* __restrict__ pv, int* __restrict__ pi) {
    __shared__ __align__(16) char lA[16384];
    __shared__ __align__(16) char lB[16384];
    __shared__ float sv[2][128];
    __shared__ int   si[2][128];
    const int t = threadIdx.x;
    const int lane = t & 63;
    const int w = t >> 6;
    const int wy = w >> 1, wx = w & 1;
    const int rowBase = blockIdx.x * 128;
    const int colBase = blockIdx.y * 128;
    const char* Ab = (const char*)A;
    const char* Bb = (const char*)B;

    f32x4 acc[4][4];
    #pragma unroll
    for (int i = 0; i < 4; ++i)
        #pragma unroll
        for (int j = 0; j < 4; ++j) acc[i][j] = (f32x4)0.0f;

    for (int step = 0; step < 12; ++step) {
        const int g0 = step * 64;
        const int term = g0 >> 8;
        const int aCol = ((term == 2) ? 256 : 0) + (g0 & 255);
        const int bCol = ((term == 1) ? 256 : 0) + (g0 & 255);
        // stage 16 KB each of A,B via global_load_lds; LDS row-major [128][64]bf16
        // with 16B-slot XOR swizzle (slot ^= row&7), pre-applied to the SOURCE.
        #pragma unroll
        for (int p = 0; p < 4; ++p) {
            int o = p * 4096 + t * 16;
            int row = o >> 7;
            int ss = ((o & 127) >> 4) ^ (row & 7);
            gload_lds16(Ab + ((size_t)(rowBase + row) * 512 + aCol + ss * 8) * 2, lA + o);
            gload_lds16(Bb + ((size_t)(colBase + row) * 512 + bCol + ss * 8) * 2, lB + o);
        }
        __syncthreads();
        #pragma unroll
        for (int ksub = 0; ksub < 2; ++ksub) {
            bf16x8 av[4], bv[4];
            #pragma unroll
            for (int mf = 0; mf < 4; ++mf) {
                int row = wy * 64 + mf * 16 + (lane & 15);
                int slot = (ksub * 4 + (lane >> 4)) ^ (row & 7);
                av[mf] = *(const bf16x8*)(lA + row * 128 + slot * 16);
            }
            #pragma unroll
            for (int nf = 0; nf < 4; ++nf) {
                int row = wx * 64 + nf * 16 + (lane & 15);
                int slot = (ksub * 4 + (lane >> 4)) ^ (row & 7);
                bv[nf] = *(const bf16x8*)(lB + row * 128 + slot * 16);
            }
            #pragma unroll
            for (int mf = 0; mf < 4; ++mf)
                #pragma unroll
                for (int nf = 0; nf < 4; ++nf)
                    acc[mf][nf] = __builtin_amdgcn_mfma_f32_16x16x32_bf16(
                        av[mf], bv[nf], acc[mf][nf], 0, 0, 0);
        }
        __syncthreads();
    }

    // epilogue: scores + per-lane argmin over the 4 col-frags
    float bvv[4][4]; int bii[4][4];   // [mf][r]
    #pragma unroll
    for (int mf = 0; mf < 4; ++mf)
        #pragma unroll
        for (int r = 0; r < 4; ++r) { bvv[mf][r] = 3.0e38f; bii[mf][r] = 0; }
    #pragma unroll
    for (int nf = 0; nf < 4; ++nf) {
        int col = colBase + wx * 64 + nf * 16 + (lane & 15);
        float s2 = sumw2[col];
        #pragma unroll
        for (int mf = 0; mf < 4; ++mf)
            #pragma unroll
            for (int r = 0; r < 4; ++r) {
                float s = s2 - 2.0f * acc[mf][nf][r];
                if (s < bvv[mf][r]) { bvv[mf][r] = s; bii[mf][r] = col; }
            }
    }
    // reduce across the 16 cols held by the lane&15 group
    #pragma unroll
    for (int mf = 0; mf < 4; ++mf)
        #pragma unroll
        for (int r = 0; r < 4; ++r) {
            float v = bvv[mf][r]; int bi = bii[mf][r];
            #pragma unroll
            for (int m = 1; m <= 8; m <<= 1) {
                float ov = __shfl_xor(v, m, 64);
                int   oi = __shfl_xor(bi, m, 64);
                if (ov < v || (ov == v && oi < bi)) { v = ov; bi = oi; }
            }
            if ((lane & 15) == 0) {
                int rl = wy * 64 + mf * 16 + (lane >> 4) * 4 + r;
                sv[wx][rl] = v; si[wx][rl] = bi;
            }
        }
    __syncthreads();
    if (t < 128) {
        float v0 = sv[0][t], v1 = sv[1][t];
        int   i0 = si[0][t], i1 = si[1][t];
        bool sel = (v1 < v0);
        pv[(size_t)blockIdx.y * N_IN + rowBase + t] = sel ? v1 : v0;
        pi[(size_t)blockIdx.y * N_IN + rowBase + t] = sel ? i1 : i0;
    }
}

// ---------------- k3: merge 32 column-block partials, histogram ----------------
__global__ void vq_merge32(const float* __restrict__ pv, const int* __restrict__ pi,
                           int* __restrict__ indices, int* __restrict__ counts) {
    int n = blockIdx.x * 256 + threadIdx.x;
    float bv = pv[n]; int bi = pi[n];
    for (int g = 1; g < 32; ++g) {
        float v = pv[(size_t)g * N_IN + n];
        int   i2 = pi[(size_t)g * N_IN + n];
        if (v < bv) { bv = v; bi = i2; }   // ascending col with g: strict < keeps lowest
    }
    indices[n] = bi;
    atomicAdd(&counts[bi], 1);
}

// ---------------- k4: write one-hot encodings directly (0s + the 1) ----------------
__global__ void vq_enc(const int* __restrict__ indices, float2* __restrict__ enc) {
    size_t f = (size_t)blockIdx.x * 256 + threadIdx.x;
    const size_t total = (size_t)N_IN * 2048;
    size_t stride = (size_t)gridDim.x * 256;
    for (; f < total; f += stride) {
        int n = (int)(f >> 11), j = (int)(f & 2047);
        int idx = indices[n];
        float2 v; v.x = 0.0f; v.y = 0.0f;
        if ((idx >> 1) == j) { if (idx & 1) v.y = 1.0f; else v.x = 1.0f; }
        enc[f] = v;
    }
}

// ---------------- k5: gather quantized, straight-through, loss partial ----------------
__global__ void vq_quant(const float* __restrict__ x, const float* __restrict__ w,
                         const int* __restrict__ indices, float* __restrict__ out,
                         float* __restrict__ lossacc) {
    const float4* gx = (const float4*)x;
    const float4* gw = (const float4*)w;
    float* q = out + 1;   // 4B-aligned only -> scalar stores
    size_t tid = (size_t)blockIdx.x * 256 + threadIdx.x;
    size_t stride = (size_t)gridDim.x * 256;
    float s = 0.0f;
    for (size_t f = tid; f < (ND / 4); f += stride) {
        int n = (int)(f >> 6), d4 = (int)(f & 63);
        float4 xv = gx[f];
        float4 ev = gw[(size_t)indices[n] * 64 + d4];
        float dx = ev.x - xv.x, dy = ev.y - xv.y, dz = ev.z - xv.z, dw = ev.w - xv.w;
        s += dx * dx + dy * dy + dz * dz + dw * dw;
        size_t o = (size_t)n * 256 + (size_t)d4 * 4;
        q[o]     = xv.x + dx;
        q[o + 1] = xv.y + dy;
        q[o + 2] = xv.z + dz;
        q[o + 3] = xv.w + dw;
    }
    #pragma unroll
    for (int off = 32; off; off >>= 1) s += __shfl_down(s, off, 64);
    if ((threadIdx.x & 63) == 0) atomicAdd(lossacc, s);
}

// ---------------- k6: finalize loss + perplexity ----------------
__global__ void vq_final(const int* __restrict__ counts, const float* __restrict__ lossacc,
                         float* __restrict__ out) {
    __shared__ float red[4];
    int t = threadIdx.x;
    float e = 0.0f;
    #pragma unroll
    for (int k = 0; k < 16; ++k) {
        float p = (float)counts[t + 256 * k] * (1.0f / 32768.0f);
        e += p * logf(p + 1e-10f);
    }
    #pragma unroll
    for (int off = 32; off; off >>= 1) e += __shfl_down(e, off, 64);
    if ((t & 63) == 0) red[t >> 6] = e;
    __syncthreads();
    if (t == 0) {
        float ent = red[0] + red[1] + red[2] + red[3];
        out[0] = 1.25f * lossacc[0] / 8388608.0f;
        out[OUT_PERP_OFF] = expf(-ent);
    }
}

extern "C" void kernel_launch(void* const* d_in, const int* in_sizes, int n_in,
                              void* d_out, int out_size, void* d_ws, size_t ws_size,
                              hipStream_t stream) {
    const float* x = (const float*)d_in[0];
    const float* w = (const float*)d_in[1];
    float* out = (float*)d_out;
    char* ws = (char*)d_ws;
    float* sumw2   = (float*)(ws + WS_SUMW2);
    int*   counts  = (int*)  (ws + WS_COUNTS);
    float* lossacc = (float*)(ws + WS_LOSS);
    int*   indices = (int*)  (ws + WS_IDX);

    // scratch lives inside the 512MB encodings output region (overwritten later)
    char* scr = (char*)d_out + (size_t)OUT_ENC_OFF * 4 + 8;   // 16B aligned
    ushort* Abuf = (ushort*)(scr + SCR_A);
    ushort* Bbuf = (ushort*)(scr + SCR_B);
    float*  pvb  = (float*) (scr + SCR_PV);
    int*    pib  = (int*)   (scr + SCR_PI);

    hipMemsetAsync(ws + WS_COUNTS, 0, 16384 + 4, stream);

    vq_convert<<<2048, 256, 0, stream>>>(x, w, Abuf, Bbuf);
    vq_sumw2<<<K_EMB / 4, 256, 0, stream>>>(w, sumw2);
    dim3 g2(N_IN / 128, K_EMB / 128);
    vq_gemm_argmin<<<g2, 256, 0, stream>>>(Abuf, Bbuf, sumw2, pvb, pib);
    vq_merge32<<<N_IN / 256, 256, 0, stream>>>(pvb, pib, indices, counts);
    vq_enc<<<8192, 256, 0, stream>>>(indices, (float2*)(out + OUT_ENC_OFF));
    vq_quant<<<2048, 256, 0, stream>>>(x, w, indices, out, lossacc);
    vq_final<<<1, 256, 0, stream>>>(counts, lossacc, out);
}

// Round 3
// 976.788 us; speedup vs baseline: 1.7253x; 1.0775x over previous
//
#include <hip/hip_runtime.h>
#include <hip/hip_bf16.h>

// ---------------- problem constants ----------------
#define N_IN    32768
#define K_EMB   4096
#define D_EMB   256
#define ND      (N_IN * (size_t)D_EMB)          // 8388608
#define NK      ((size_t)N_IN * K_EMB)          // 134217728
// d_out layout (floats): [0]=loss, [1..1+ND)=quantized_st, [1+ND]=perplexity, [2+ND..)=encodings
#define OUT_PERP_OFF  (1 + ND)                  // 8388609
#define OUT_ENC_OFF   (2 + ND)                  // 8388610

#define W_SCALE 4096.0f

// ---------------- small ws layout (bytes) ----------------
#define WS_SUMB2   0          // 4096 f
#define WS_COUNTS  16384      // 4096 i
#define WS_LOSS    32768      // 1 f
#define WS_IDX     36864      // 32768 i

// scratch inside encodings region (bytes from scratch base, 16B aligned):
//   A' = [x_hi | x_lo]  N x 512 fp16  = 33554432 B
//   B' = fp16(w*4096)   K x 256 fp16  =  2097152 B
//   PV 16x32768 f32 = 2 MB ; PI same
#define SCR_A   0
#define SCR_B   33554432
#define SCR_PV  35651584
#define SCR_PI  37748736

typedef _Float16 f16x8 __attribute__((ext_vector_type(8)));
typedef float    f32x4 __attribute__((ext_vector_type(4)));

__device__ __forceinline__ void gload_lds16(const void* g, void* l) {
    __builtin_amdgcn_global_load_lds(
        (const __attribute__((address_space(1))) unsigned int*)g,
        (__attribute__((address_space(3))) unsigned int*)l, 16, 0, 0);
}

__device__ __forceinline__ ushort h_bits(_Float16 h) {
    union { _Float16 h; ushort u; } cv; cv.h = h; return cv.u;
}
__device__ __forceinline__ float h_val(ushort u) {
    union { ushort u; _Float16 h; } cv; cv.u = u; return (float)cv.h;
}
__device__ __forceinline__ void split_f16(float v, ushort& hi, ushort& lo) {
    _Float16 h = (_Float16)v;
    hi = h_bits(h);
    lo = h_bits((_Float16)(v - (float)h));
}

// ---------------- k0: fp32 -> fp16 two-term x, fp16 scaled w ----------------
__global__ void vq_convert(const float* __restrict__ x, const float* __restrict__ w,
                           ushort* __restrict__ A, ushort* __restrict__ B) {
    const size_t XQ = ND / 4;                       // 2097152 float4's of x
    const size_t WQ = (size_t)K_EMB * D_EMB / 4;    // 262144
    size_t f = (size_t)blockIdx.x * 256 + threadIdx.x;
    size_t stride = (size_t)gridDim.x * 256;
    for (; f < XQ + WQ; f += stride) {
        if (f < XQ) {
            int n = (int)(f >> 6), d4 = (int)(f & 63);
            float4 v = ((const float4*)x)[f];
            ushort4 hv, lv;
            split_f16(v.x, hv.x, lv.x); split_f16(v.y, hv.y, lv.y);
            split_f16(v.z, hv.z, lv.z); split_f16(v.w, hv.w, lv.w);
            *(ushort4*)(A + (size_t)n * 512 + d4 * 4)       = hv;
            *(ushort4*)(A + (size_t)n * 512 + 256 + d4 * 4) = lv;
        } else {
            size_t f2 = f - XQ;
            int c = (int)(f2 >> 6), d4 = (int)(f2 & 63);
            float4 v = ((const float4*)w)[f2];
            ushort4 s;
            s.x = h_bits((_Float16)(v.x * W_SCALE));
            s.y = h_bits((_Float16)(v.y * W_SCALE));
            s.z = h_bits((_Float16)(v.z * W_SCALE));
            s.w = h_bits((_Float16)(v.w * W_SCALE));
            *(ushort4*)(B + (size_t)c * 256 + d4 * 4) = s;
        }
    }
}

// ---------------- k1: sum of squares of the STORED fp16 codewords ----------------
__global__ void vq_sumb2(const ushort* __restrict__ B, float* __restrict__ sumb2) {
    int lane = threadIdx.x & 63;
    int row  = blockIdx.x * 4 + (threadIdx.x >> 6);
    ushort4 v = ((const ushort4*)B)[(size_t)row * 64 + lane];
    float a = h_val(v.x), b = h_val(v.y), c = h_val(v.z), d = h_val(v.w);
    float s = a * a + b * b + c * c + d * d;
    #pragma unroll
    for (int off = 32; off; off >>= 1) s += __shfl_down(s, off, 64);
    if (lane == 0) sumb2[row] = s;
}

// ---------------- k2: fp16 MFMA GEMM (256x256 tile, 2-phase) + fused argmin ----
// score(n,c) = sumb2[c] - 2*W_SCALE*dot(x_n, w~_c),   Kred = 512 ([x_hi|x_lo] vs [w~|w~])
__global__ __launch_bounds__(512, 2) void vq_gemm_argmin(
        const ushort* __restrict__ A, const ushort* __restrict__ B,
        const float* __restrict__ sumb2,
        float* __restrict__ pv, int* __restrict__ pi) {
    __shared__ __align__(16) char lds[131072];     // lA[2]:0,32K  lB[2]:64K,96K
    const int t = threadIdx.x;
    const int lane = t & 63;
    const int wv = t >> 6;
    const int wy = wv >> 2, wx = wv & 3;           // wave tile: 128 rows x 64 cols
    const int rowBase = blockIdx.x * 256;
    const int colBase = blockIdx.y * 256;
    const char* Ab = (const char*)A;
    const char* Bb = (const char*)B;

    f32x4 acc[8][4];
    #pragma unroll
    for (int i = 0; i < 8; ++i)
        #pragma unroll
        for (int j = 0; j < 4; ++j) acc[i][j] = (f32x4)0.0f;

    // stage one 256x64 fp16 tile of A and B into buf (32KB each), source-swizzled
    #define STAGE(buf, step) {                                                        \
        const int aCol = (step) * 64;                                                 \
        const int bCol = ((step) * 64) & 255;                                         \
        char* la = lds + (buf) * 32768;                                               \
        char* lb = lds + 65536 + (buf) * 32768;                                       \
        _Pragma("unroll")                                                             \
        for (int p = 0; p < 4; ++p) {                                                 \
            int o = p * 8192 + t * 16;                                                \
            int row = o >> 7;                                                         \
            int ss = ((o & 127) >> 4) ^ (row & 7);                                    \
            gload_lds16(Ab + ((size_t)(rowBase + row) * 512 + aCol + ss * 8) * 2, la + o); \
            gload_lds16(Bb + ((size_t)(colBase + row) * 256 + bCol + ss * 8) * 2, lb + o); \
        }                                                                             \
    }

    STAGE(0, 0);
    __syncthreads();
    for (int step = 0; step < 8; ++step) {
        const int cur = step & 1;
        if (step < 7) STAGE(cur ^ 1, step + 1);
        const char* la = lds + cur * 32768;
        const char* lb = lds + 65536 + cur * 32768;
        #pragma unroll
        for (int ksub = 0; ksub < 2; ++ksub) {
            f16x8 av[8], bv[4];
            #pragma unroll
            for (int mf = 0; mf < 8; ++mf) {
                int row = wy * 128 + mf * 16 + (lane & 15);
                int slot = (ksub * 4 + (lane >> 4)) ^ (row & 7);
                av[mf] = *(const f16x8*)(la + row * 128 + slot * 16);
            }
            #pragma unroll
            for (int nf = 0; nf < 4; ++nf) {
                int row = wx * 64 + nf * 16 + (lane & 15);
                int slot = (ksub * 4 + (lane >> 4)) ^ (row & 7);
                bv[nf] = *(const f16x8*)(lb + row * 128 + slot * 16);
            }
            #pragma unroll
            for (int mf = 0; mf < 8; ++mf)
                #pragma unroll
                for (int nf = 0; nf < 4; ++nf)
                    acc[mf][nf] = __builtin_amdgcn_mfma_f32_16x16x32_f16(
                        av[mf], bv[nf], acc[mf][nf], 0, 0, 0);
        }
        __syncthreads();
    }

    // epilogue: scores + per-lane argmin, then 16-lane group reduce, then 4 wx waves
    float s2[4];
    #pragma unroll
    for (int nf = 0; nf < 4; ++nf)
        s2[nf] = sumb2[colBase + wx * 64 + nf * 16 + (lane & 15)];

    float* sv = (float*)lds;              // [4][256]
    int*   si = (int*)(lds + 4096);       // [4][256]
    #pragma unroll
    for (int mf = 0; mf < 8; ++mf) {
        #pragma unroll
        for (int r = 0; r < 4; ++r) {
            float bvv = 3.0e38f; int bii = 0;
            #pragma unroll
            for (int nf = 0; nf < 4; ++nf) {
                int col = colBase + wx * 64 + nf * 16 + (lane & 15);
                float s = s2[nf] - (2.0f * W_SCALE) * acc[mf][nf][r];
                if (s < bvv) { bvv = s; bii = col; }
            }
            #pragma unroll
            for (int m = 1; m <= 8; m <<= 1) {
                float ov = __shfl_xor(bvv, m, 64);
                int   oi = __shfl_xor(bii, m, 64);
                if (ov < bvv || (ov == bvv && oi < bii)) { bvv = ov; bii = oi; }
            }
            if ((lane & 15) == 0) {
                int rl = wy * 128 + mf * 16 + (lane >> 4) * 4 + r;
                sv[wx * 256 + rl] = bvv;
                si[wx * 256 + rl] = bii;
            }
        }
    }
    __syncthreads();
    if (t < 256) {
        float bv2 = sv[t]; int bi2 = si[t];
        #pragma unroll
        for (int g = 1; g < 4; ++g) {
            float v = sv[g * 256 + t];
            int   i2 = si[g * 256 + t];
            if (v < bv2) { bv2 = v; bi2 = i2; }   // cols ascend with g: strict < keeps lowest
        }
        pv[(size_t)blockIdx.y * N_IN + rowBase + t] = bv2;
        pi[(size_t)blockIdx.y * N_IN + rowBase + t] = bi2;
    }
}

// ---------------- k3: merge 16 column-block partials, histogram ----------------
__global__ void vq_merge16(const float* __restrict__ pv, const int* __restrict__ pi,
                           int* __restrict__ indices, int* __restrict__ counts) {
    int n = blockIdx.x * 256 + threadIdx.x;
    float bv = pv[n]; int bi = pi[n];
    for (int g = 1; g < 16; ++g) {
        float v = pv[(size_t)g * N_IN + n];
        int   i2 = pi[(size_t)g * N_IN + n];
        if (v < bv) { bv = v; bi = i2; }
    }
    indices[n] = bi;
    atomicAdd(&counts[bi], 1);
}

// ---------------- k4: write one-hot encodings directly (0s + the 1) ----------------
__global__ void vq_enc(const int* __restrict__ indices, float2* __restrict__ enc) {
    size_t f = (size_t)blockIdx.x * 256 + threadIdx.x;
    const size_t total = (size_t)N_IN * 2048;
    size_t stride = (size_t)gridDim.x * 256;
    for (; f < total; f += stride) {
        int n = (int)(f >> 11), j = (int)(f & 2047);
        int idx = indices[n];
        float2 v; v.x = 0.0f; v.y = 0.0f;
        if ((idx >> 1) == j) { if (idx & 1) v.y = 1.0f; else v.x = 1.0f; }
        enc[f] = v;
    }
}

// ---------------- k5: gather quantized, straight-through, loss partial ----------------
__global__ void vq_quant(const float* __restrict__ x, const float* __restrict__ w,
                         const int* __restrict__ indices, float* __restrict__ out,
                         float* __restrict__ lossacc) {
    const float4* gx = (const float4*)x;
    const float4* gw = (const float4*)w;
    float* q = out + 1;   // 4B-aligned only -> scalar stores
    size_t tid = (size_t)blockIdx.x * 256 + threadIdx.x;
    size_t stride = (size_t)gridDim.x * 256;
    float s = 0.0f;
    for (size_t f = tid; f < (ND / 4); f += stride) {
        int n = (int)(f >> 6), d4 = (int)(f & 63);
        float4 xv = gx[f];
        float4 ev = gw[(size_t)indices[n] * 64 + d4];
        float dx = ev.x - xv.x, dy = ev.y - xv.y, dz = ev.z - xv.z, dw = ev.w - xv.w;
        s += dx * dx + dy * dy + dz * dz + dw * dw;
        size_t o = (size_t)n * 256 + (size_t)d4 * 4;
        q[o]     = xv.x + dx;
        q[o + 1] = xv.y + dy;
        q[o + 2] = xv.z + dz;
        q[o + 3] = xv.w + dw;
    }
    #pragma unroll
    for (int off = 32; off; off >>= 1) s += __shfl_down(s, off, 64);
    if ((threadIdx.x & 63) == 0) atomicAdd(lossacc, s);
}

// ---------------- k6: finalize loss + perplexity ----------------
__global__ void vq_final(const int* __restrict__ counts, const float* __restrict__ lossacc,
                         float* __restrict__ out) {
    __shared__ float red[4];
    int t = threadIdx.x;
    float e = 0.0f;
    #pragma unroll
    for (int k = 0; k < 16; ++k) {
        float p = (float)counts[t + 256 * k] * (1.0f / 32768.0f);
        e += p * logf(p + 1e-10f);
    }
    #pragma unroll
    for (int off = 32; off; off >>= 1) e += __shfl_down(e, off, 64);
    if ((t & 63) == 0) red[t >> 6] = e;
    __syncthreads();
    if (t == 0) {
        float ent = red[0] + red[1] + red[2] + red[3];
        out[0] = 1.25f * lossacc[0] / 8388608.0f;
        out[OUT_PERP_OFF] = expf(-ent);
    }
}

extern "C" void kernel_launch(void* const* d_in, const int* in_sizes, int n_in,
                              void* d_out, int out_size, void* d_ws, size_t ws_size,
                              hipStream_t stream) {
    const float* x = (const float*)d_in[0];
    const float* w = (const float*)d_in[1];
    float* out = (float*)d_out;
    char* ws = (char*)d_ws;
    float* sumb2   = (float*)(ws + WS_SUMB2);
    int*   counts  = (int*)  (ws + WS_COUNTS);
    float* lossacc = (float*)(ws + WS_LOSS);
    int*   indices = (int*)  (ws + WS_IDX);

    // scratch lives inside the 512MB encodings output region (overwritten later)
    char* scr = (char*)d_out + (size_t)OUT_ENC_OFF * 4 + 8;   // 16B aligned
    ushort* Abuf = (ushort*)(scr + SCR_A);
    ushort* Bbuf = (ushort*)(scr + SCR_B);
    float*  pvb  = (float*) (scr + SCR_PV);
    int*    pib  = (int*)   (scr + SCR_PI);

    hipMemsetAsync(ws + WS_COUNTS, 0, 16384 + 4, stream);

    vq_convert<<<2048, 256, 0, stream>>>(x, w, Abuf, Bbuf);
    vq_sumb2<<<K_EMB / 4, 256, 0, stream>>>(Bbuf, sumb2);
    dim3 g2(N_IN / 256, K_EMB / 256);
    vq_gemm_argmin<<<g2, 512, 0, stream>>>(Abuf, Bbuf, sumb2, pvb, pib);
    vq_merge16<<<N_IN / 256, 256, 0, stream>>>(pvb, pib, indices, counts);
    vq_enc<<<8192, 256, 0, stream>>>(indices, (float2*)(out + OUT_ENC_OFF));
    vq_quant<<<2048, 256, 0, stream>>>(x, w, indices, out, lossacc);
    vq_final<<<1, 256, 0, stream>>>(counts, lossacc, out);
}

// Round 7
// 825.895 us; speedup vs baseline: 2.0406x; 1.1827x over previous
//
#include <hip/hip_runtime.h>
#include <hip/hip_bf16.h>

// ---------------- problem constants ----------------
#define N_IN    32768
#define K_EMB   4096
#define D_EMB   256
#define ND      (N_IN * (size_t)D_EMB)          // 8388608
#define NK      ((size_t)N_IN * K_EMB)          // 134217728
// d_out layout (floats): [0]=loss, [1..1+ND)=quantized_st, [1+ND]=perplexity, [2+ND..)=encodings
#define OUT_PERP_OFF  (1 + ND)                  // 8388609
#define OUT_ENC_OFF   (2 + ND)                  // 8388610

#define W_SCALE 4096.0f

// ---------------- small ws layout (bytes) ----------------
#define WS_SUMB2   0          // 4096 f
#define WS_COUNTS  16384      // 4096 i
#define WS_LOSS    32768      // 1 f
#define WS_IDX     36864      // 32768 i (131072 B)

typedef _Float16 f16x8 __attribute__((ext_vector_type(8)));
typedef float    f32x4 __attribute__((ext_vector_type(4)));

__device__ __forceinline__ void gload_lds16(const void* g, void* l) {
    __builtin_amdgcn_global_load_lds(
        (const __attribute__((address_space(1))) unsigned int*)g,
        (__attribute__((address_space(3))) unsigned int*)l, 16, 0, 0);
}

__device__ __forceinline__ ushort h_bits(_Float16 h) {
    union { _Float16 h; ushort u; } cv; cv.h = h; return cv.u;
}
__device__ __forceinline__ float h_val(ushort u) {
    union { ushort u; _Float16 h; } cv; cv.u = u; return (float)cv.h;
}

// ---------------- k0: w -> fp16(w*4096), layout [c][256] ----------------
__global__ void vq_convw(const float* __restrict__ w, ushort* __restrict__ B) {
    int f = blockIdx.x * 256 + threadIdx.x;    // 0..262143 float4s
    float4 v = ((const float4*)w)[f];
    ushort4 s;
    s.x = h_bits((_Float16)(v.x * W_SCALE));
    s.y = h_bits((_Float16)(v.y * W_SCALE));
    s.z = h_bits((_Float16)(v.z * W_SCALE));
    s.w = h_bits((_Float16)(v.w * W_SCALE));
    ((ushort4*)B)[f] = s;
}

// ---------------- k1: sum of squares of the STORED fp16 codewords ----------------
__global__ void vq_sumb2(const ushort* __restrict__ B, float* __restrict__ sumb2) {
    int lane = threadIdx.x & 63;
    int row  = blockIdx.x * 4 + (threadIdx.x >> 6);
    ushort4 v = ((const ushort4*)B)[(size_t)row * 64 + lane];
    float a = h_val(v.x), b = h_val(v.y), c = h_val(v.z), d = h_val(v.w);
    float s = a * a + b * b + c * c + d * d;
    #pragma unroll
    for (int off = 32; off; off >>= 1) s += __shfl_down(s, off, 64);
    if (lane == 0) sumb2[row] = s;
}

// ---------------- k2: persistent-block fp16 MFMA GEMM + full fused argmin ------
// grid = 256 blocks (1/CU). Block: 128 rows x ALL 4096 cols, K=256.
// LDS: A panel 64KB (resident, swizzled) | B dbuf 2x32KB | sumb2 16KB = 144KB.
// score(n,c) = sumb2[c] - 2*W_SCALE*dot(x16_n, w~_c)   (scaled by S^2: argmin-invariant)
__global__ __launch_bounds__(512, 2) void vq_gemm_argmin(
        const float* __restrict__ x, const ushort* __restrict__ Bw,
        const float* __restrict__ sumb2,
        int* __restrict__ indices, int* __restrict__ counts) {
    __shared__ __align__(16) char lds[147456];
    const int t = threadIdx.x;
    const int lane = t & 63;
    const int wv = t >> 6;
    const int wy = wv >> 2, wx = wv & 3;       // wave tile: 64 rows x 64 cols per pass
    const int rowBase = blockIdx.x * 128;
    const char* Bb = (const char*)Bw;

    // ---- prologue: A fp32->fp16 into LDS (swizzled), sumb2 + first B chunk ----
    {
        const float4* gx = (const float4*)x;
        #pragma unroll
        for (int p = 0; p < 16; ++p) {
            int idx = p * 512 + t;              // float4 index in 128x64 panel
            int row = idx >> 6, k4 = idx & 63;
            float4 v = gx[(size_t)rowBase * 64 + idx];
            ushort4 h;
            h.x = h_bits((_Float16)v.x); h.y = h_bits((_Float16)v.y);
            h.z = h_bits((_Float16)v.z); h.w = h_bits((_Float16)v.w);
            int slot = (k4 >> 1) ^ (row & 7);   // 16B-slot XOR swizzle within row
            *(ushort4*)(lds + row * 512 + slot * 16 + (k4 & 1) * 8) = h;
        }
        #pragma unroll
        for (int p = 0; p < 2; ++p) {           // sumb2 -> LDS (16 KB, linear)
            int o = p * 8192 + t * 16;
            gload_lds16((const char*)sumb2 + o, lds + 131072 + o);
        }
        #pragma unroll
        for (int p = 0; p < 4; ++p) {           // first B chunk (ct=0, ks=0)
            int o = p * 8192 + t * 16;
            int row = o >> 7;
            int ss = ((o & 127) >> 4) ^ (row & 7);
            gload_lds16(Bb + ((size_t)row * 256 + ss * 8) * 2, lds + 65536 + o);
        }
    }
    __syncthreads();

    f32x4 acc[4][4];
    float bv_[4][4]; int bi_[4][4];             // running best per [mf][r]
    #pragma unroll
    for (int i = 0; i < 4; ++i)
        #pragma unroll
        for (int j = 0; j < 4; ++j) { acc[i][j] = (f32x4)0.0f; bv_[i][j] = 3.0e38f; bi_[i][j] = 0; }

    #pragma unroll 4
    for (int u = 0; u < 64; ++u) {              // u = ct*4 + ks
        const int ks = u & 3, ct = u >> 2;
        const char* lb = lds + 65536 + (u & 1) * 32768;
        if (u < 63) {                           // prefetch next B chunk
            const int un = u + 1;
            char* lbn = lds + 65536 + (un & 1) * 32768;
            const size_t srcBase = (size_t)(un >> 2) * 65536 + (size_t)(un & 3) * 64;
            #pragma unroll
            for (int p = 0; p < 4; ++p) {
                int o = p * 8192 + t * 16;
                int row = o >> 7;
                int ss = ((o & 127) >> 4) ^ (row & 7);
                gload_lds16(Bb + (srcBase + (size_t)row * 256 + ss * 8) * 2, lbn + o);
            }
        }
        #pragma unroll
        for (int kk = 0; kk < 2; ++kk) {
            f16x8 av[4], bvv[4];
            #pragma unroll
            for (int mf = 0; mf < 4; ++mf) {
                int row = wy * 64 + mf * 16 + (lane & 15);
                int slot = ks * 8 + ((kk * 4 + (lane >> 4)) ^ (row & 7));
                av[mf] = *(const f16x8*)(lds + row * 512 + slot * 16);
            }
            #pragma unroll
            for (int nf = 0; nf < 4; ++nf) {
                int col = wx * 64 + nf * 16 + (lane & 15);
                int slot = (kk * 4 + (lane >> 4)) ^ (col & 7);
                bvv[nf] = *(const f16x8*)(lb + col * 128 + slot * 16);
            }
            #pragma unroll
            for (int mf = 0; mf < 4; ++mf)
                #pragma unroll
                for (int nf = 0; nf < 4; ++nf)
                    acc[mf][nf] = __builtin_amdgcn_mfma_f32_16x16x32_f16(
                        av[mf], bvv[nf], acc[mf][nf], 0, 0, 0);
        }
        __syncthreads();
        if (ks == 3) {                          // col-tile epilogue: fold into running argmin
            #pragma unroll
            for (int nf = 0; nf < 4; ++nf) {
                int col = ct * 256 + wx * 64 + nf * 16 + (lane & 15);
                float s2 = *(const float*)(lds + 131072 + ((size_t)col << 2));
                #pragma unroll
                for (int mf = 0; mf < 4; ++mf)
                    #pragma unroll
                    for (int r = 0; r < 4; ++r) {
                        float s = s2 - (2.0f * W_SCALE) * acc[mf][nf][r];
                        if (s < bv_[mf][r]) { bv_[mf][r] = s; bi_[mf][r] = col; }
                        acc[mf][nf][r] = 0.0f;
                    }
            }
        }
    }

    // ---- final reduce: 16-lane col groups, then 4 col-waves via LDS ----
    float* sv = (float*)(lds + 65536);          // [4][128]  (B buf0 region, post-barrier)
    int*   si = (int*)  (lds + 65536 + 2048);
    #pragma unroll
    for (int mf = 0; mf < 4; ++mf)
        #pragma unroll
        for (int r = 0; r < 4; ++r) {
            float v = bv_[mf][r]; int bi = bi_[mf][r];
            #pragma unroll
            for (int m = 1; m <= 8; m <<= 1) {
                float ov = __shfl_xor(v, m, 64);
                int   oi = __shfl_xor(bi, m, 64);
                if (ov < v || (ov == v && oi < bi)) { v = ov; bi = oi; }
            }
            if ((lane & 15) == 0) {
                int rl = wy * 64 + mf * 16 + (lane >> 4) * 4 + r;
                sv[wx * 128 + rl] = v;
                si[wx * 128 + rl] = bi;
            }
        }
    __syncthreads();
    if (t < 128) {
        float v = sv[t]; int bi = si[t];
        #pragma unroll
        for (int g = 1; g < 4; ++g) {           // cols ascend with g: strict < keeps lowest
            float ov = sv[g * 128 + t]; int oi = si[g * 128 + t];
            if (ov < v) { v = ov; bi = oi; }
        }
        indices[rowBase + t] = bi;
        atomicAdd(&counts[bi], 1);
    }
}

// ---------------- k4: write one-hot encodings directly (0s + the 1) ----------------
__global__ void vq_enc(const int* __restrict__ indices, float2* __restrict__ enc) {
    size_t f = (size_t)blockIdx.x * 256 + threadIdx.x;
    const size_t total = (size_t)N_IN * 2048;
    size_t stride = (size_t)gridDim.x * 256;
    for (; f < total; f += stride) {
        int n = (int)(f >> 11), j = (int)(f & 2047);
        int idx = indices[n];
        float2 v; v.x = 0.0f; v.y = 0.0f;
        if ((idx >> 1) == j) { if (idx & 1) v.y = 1.0f; else v.x = 1.0f; }
        enc[f] = v;
    }
}

// ---------------- k5: gather quantized, straight-through, loss partial ----------------
__global__ void vq_quant(const float* __restrict__ x, const float* __restrict__ w,
                         const int* __restrict__ indices, float* __restrict__ out,
                         float* __restrict__ lossacc) {
    const float4* gx = (const float4*)x;
    const float4* gw = (const float4*)w;
    float* q = out + 1;   // 4B-aligned only -> scalar stores
    size_t tid = (size_t)blockIdx.x * 256 + threadIdx.x;
    size_t stride = (size_t)gridDim.x * 256;
    float s = 0.0f;
    for (size_t f = tid; f < (ND / 4); f += stride) {
        int n = (int)(f >> 6), d4 = (int)(f & 63);
        float4 xv = gx[f];
        float4 ev = gw[(size_t)indices[n] * 64 + d4];
        float dx = ev.x - xv.x, dy = ev.y - xv.y, dz = ev.z - xv.z, dw = ev.w - xv.w;
        s += dx * dx + dy * dy + dz * dz + dw * dw;
        size_t o = (size_t)n * 256 + (size_t)d4 * 4;
        q[o]     = xv.x + dx;
        q[o + 1] = xv.y + dy;
        q[o + 2] = xv.z + dz;
        q[o + 3] = xv.w + dw;
    }
    #pragma unroll
    for (int off = 32; off; off >>= 1) s += __shfl_down(s, off, 64);
    if ((threadIdx.x & 63) == 0) atomicAdd(lossacc, s);
}

// ---------------- k6: finalize loss + perplexity ----------------
__global__ void vq_final(const int* __restrict__ counts, const float* __restrict__ lossacc,
                         float* __restrict__ out) {
    __shared__ float red[4];
    int t = threadIdx.x;
    float e = 0.0f;
    #pragma unroll
    for (int k = 0; k < 16; ++k) {
        float p = (float)counts[t + 256 * k] * (1.0f / 32768.0f);
        e += p * logf(p + 1e-10f);
    }
    #pragma unroll
    for (int off = 32; off; off >>= 1) e += __shfl_down(e, off, 64);
    if ((t & 63) == 0) red[t >> 6] = e;
    __syncthreads();
    if (t == 0) {
        float ent = red[0] + red[1] + red[2] + red[3];
        out[0] = 1.25f * lossacc[0] / 8388608.0f;
        out[OUT_PERP_OFF] = expf(-ent);
    }
}

extern "C" void kernel_launch(void* const* d_in, const int* in_sizes, int n_in,
                              void* d_out, int out_size, void* d_ws, size_t ws_size,
                              hipStream_t stream) {
    const float* x = (const float*)d_in[0];
    const float* w = (const float*)d_in[1];
    float* out = (float*)d_out;
    char* ws = (char*)d_ws;
    float* sumb2   = (float*)(ws + WS_SUMB2);
    int*   counts  = (int*)  (ws + WS_COUNTS);
    float* lossacc = (float*)(ws + WS_LOSS);
    int*   indices = (int*)  (ws + WS_IDX);

    // B' (2 MB) lives at the start of the encodings output region (overwritten by vq_enc later)
    ushort* Bbuf = (ushort*)((char*)d_out + (size_t)OUT_ENC_OFF * 4 + 8);   // 16B aligned

    hipMemsetAsync(ws + WS_COUNTS, 0, 16384 + 4, stream);

    vq_convw<<<1024, 256, 0, stream>>>(w, Bbuf);
    vq_sumb2<<<K_EMB / 4, 256, 0, stream>>>(Bbuf, sumb2);
    vq_gemm_argmin<<<N_IN / 128, 512, 0, stream>>>(x, Bbuf, sumb2, indices, counts);
    vq_enc<<<8192, 256, 0, stream>>>(indices, (float2*)(out + OUT_ENC_OFF));
    vq_quant<<<2048, 256, 0, stream>>>(x, w, indices, out, lossacc);
    vq_final<<<1, 256, 0, stream>>>(counts, lossacc, out);
}